// Round 14
// baseline (60.838 us; speedup 1.0000x reference)
//
#include <hip/hip_runtime.h>
#include <hip/hip_bf16.h>

#define K_DIM 8192
#define L_DIM 1024
#define C2 240
#define MSTRIDE 256                 // padded m stride in partials
#define BM 128
#define BN 128
#define BK 64
#define KSPLIT 16
#define KCHUNK 512                  // K_DIM / KSPLIT
#define NSTEP 8                     // KCHUNK / BK
#define DEPTH 4                     // register-prefetch depth (was 2)
#define PART_KC (L_DIM * MSTRIDE)   // 262144 bf16 elems per k-chunk
#define PART_BYTES ((size_t)KSPLIT * PART_KC * 2)  // 8,388,608
#define TOT_F4 (10000 * 256)

typedef __attribute__((ext_vector_type(4))) float f32x4;
typedef __attribute__((ext_vector_type(2))) float f32x2;
typedef __attribute__((ext_vector_type(8))) short bf16x8;
typedef __attribute__((ext_vector_type(4))) short bf16x4;

__device__ __forceinline__ unsigned short f2bf(float f) {
  return __builtin_bit_cast(unsigned short, __float2bfloat16(f));
}
__device__ __forceinline__ float bf2f(unsigned short h) {
  unsigned u = ((unsigned)h) << 16;
  return __builtin_bit_cast(float, u);
}

// lgkm-only barrier: ds ops visible across the barrier, but in-flight GLOBAL
// loads stay pending (HIP __syncthreads emits s_waitcnt vmcnt(0) — with
// DEPTH=4 that would drain 36 outstanding loads every step).
__device__ __forceinline__ void barrier_lgkm_only() {
  __builtin_amdgcn_sched_barrier(0);
  asm volatile("s_waitcnt lgkmcnt(0)" ::: "memory");
  __builtin_amdgcn_s_barrier();
  __builtin_amdgcn_sched_barrier(0);
}

// ---------------- Stage 1: bf16 MFMA K-split GEMM, depth-4 prefetch --------
// part[kc][n][m(pad 256)] = (W[240][8192] @ A[8192][1024]) k-chunk partials.
// 256 blocks x 512 thr (8 waves: 2m x 4n of 64x32). KSPLIT=16, NSTEP=8.
// THEORY UNDER TEST: step time == congested-load-latency / DEPTH. Loads for
// step s+4 issue at step s; consumed by staging(s+4) under counted vmcnt.
// Reg slot (s&3) is read by staging(s) before issue(s+4) refills it (in-order).
__global__ __launch_bounds__(512, 2) void k_gemm(
    const float* __restrict__ Wm, const float* __restrict__ Am,
    unsigned short* __restrict__ part)
{
  __shared__ __align__(16) unsigned short sW[2 * BM * BK];  // 32 KB dbuf
  __shared__ __align__(16) unsigned short sA[2 * BN * BK];  // 32 KB dbuf

  const int t    = threadIdx.x;
  const int lane = t & 63;
  const int bid  = blockIdx.x;

  // XCD-chunked remap (bijective, 256 % 8 == 0): XCD owns 2 kc x all tiles.
  const int wk    = (bid & 7) * 32 + (bid >> 3);
  const int nt8   = wk & 7;
  const int mtile = (wk >> 3) & 1;
  const int kc    = wk >> 4;            // 0..15

  const int wid = t >> 6;
  const int mg  = wid >> 2;       // 2 groups of 64 m
  const int ng  = wid & 3;        // 4 groups of 32 n
  const int l15 = lane & 15;
  const int lk8 = (lane >> 4) * 8;

  const int n0b = nt8 * BN;
  const int m0b = mtile * BM;
  const int k0  = kc * KCHUNK;

  // W staging: thread -> (row t>>2, 16 k at (t&3)*16); 4 f32x4 loads.
  const int swm = t >> 2;
  const int swk = (t & 3) * 16;
  // A staging: thread -> (2 cols at 2*(t&63), 8 k at wid*8); 8 f32x2 loads.
  const int san = (t & 63) * 2;
  const int sak = (t >> 6) * 8;

  const float* wp = Wm + (size_t)(m0b + swm) * K_DIM + k0 + swk;
  const float* ap = Am + (size_t)(k0 + sak) * L_DIM + n0b + san;
  const bool wok = (m0b + swm) < C2;

  f32x4 wregs[DEPTH][4];
  f32x2 aregs[DEPTH][8];
  f32x4 acc[4][2];
#pragma unroll
  for (int i = 0; i < 4; ++i)
#pragma unroll
    for (int j = 0; j < 2; ++j) acc[i][j] = (f32x4){0.f, 0.f, 0.f, 0.f};

  // prologue: issue loads for steps 0..3 (depth-4)
#pragma unroll
  for (int p = 0; p < DEPTH; ++p) {
#pragma unroll
    for (int j = 0; j < 4; ++j)
      wregs[p][j] = wok ? *(const f32x4*)(wp + p * BK + 4 * j)
                        : (f32x4){0.f, 0.f, 0.f, 0.f};
#pragma unroll
    for (int r = 0; r < 8; ++r)
      aregs[p][r] = *(const f32x2*)(ap + (size_t)(p * BK + r) * L_DIM);
  }

#pragma unroll
  for (int s = 0; s < NSTEP; ++s) {
    unsigned short* swb = sW + (s & 1) * (BM * BK);
    unsigned short* sab = sA + (s & 1) * (BN * BK);
    const int slot = s & (DEPTH - 1);

    // ---- convert + swizzled LDS write from reg slot (counted vmcnt) ----
#pragma unroll
    for (int j = 0; j < 2; ++j) {       // two bf16x8 per thread (16 k)
      f32x4 a = wregs[slot][2 * j], b = wregs[slot][2 * j + 1];
      bf16x8 v;
      v[0] = (short)f2bf(a[0]); v[1] = (short)f2bf(a[1]);
      v[2] = (short)f2bf(a[2]); v[3] = (short)f2bf(a[3]);
      v[4] = (short)f2bf(b[0]); v[5] = (short)f2bf(b[1]);
      v[6] = (short)f2bf(b[2]); v[7] = (short)f2bf(b[3]);
      *(bf16x8*)&swb[swm * BK + ((swk + 8 * j) ^ ((swm & 7) << 3))] = v;
    }
#pragma unroll
    for (int j = 0; j < 2; ++j) {       // two cols, 8 k each
      const int n = san + j;
      bf16x8 v;
#pragma unroll
      for (int r = 0; r < 8; ++r)
        v[r] = (short)f2bf(j ? aregs[slot][r][1] : aregs[slot][r][0]);
      *(bf16x8*)&sab[n * BK + (sak ^ ((n & 7) << 3))] = v;
    }

    barrier_lgkm_only();   // keeps the 36 prefetch loads in flight

    // ---- issue loads for step s+4 into the just-freed slot ----
    if (s + DEPTH < NSTEP) {
      const float* wp2 = wp + (s + DEPTH) * BK;
      const float* ap2 = ap + (size_t)(s + DEPTH) * BK * L_DIM;
#pragma unroll
      for (int j = 0; j < 4; ++j)
        wregs[slot][j] = wok ? *(const f32x4*)(wp2 + 4 * j)
                             : (f32x4){0.f, 0.f, 0.f, 0.f};
#pragma unroll
      for (int r = 0; r < 8; ++r)
        aregs[slot][r] = *(const f32x2*)(ap2 + (size_t)r * L_DIM);
    }

    // ---- compute from LDS buffer s&1 ----
#pragma unroll
    for (int kk = 0; kk < BK; kk += 32) {
      bf16x8 wf[4], af[2];
#pragma unroll
      for (int mt = 0; mt < 4; ++mt) {
        int m = mg * 64 + mt * 16 + l15;
        wf[mt] = *(const bf16x8*)&swb[m * BK + ((kk + lk8) ^ ((m & 7) << 3))];
      }
#pragma unroll
      for (int nt = 0; nt < 2; ++nt) {
        int n = ng * 32 + nt * 16 + l15;
        af[nt] = *(const bf16x8*)&sab[n * BK + ((kk + lk8) ^ ((n & 7) << 3))];
      }
#pragma unroll
      for (int mt = 0; mt < 4; ++mt)
#pragma unroll
        for (int nt = 0; nt < 2; ++nt)
          acc[mt][nt] = __builtin_amdgcn_mfma_f32_16x16x32_bf16(
              wf[mt], af[nt], acc[mt][nt], 0, 0, 0);
    }
    // single barrier/step: next iteration writes the other LDS buffer
  }

  // ---- store transposed bf16 partials: part[kc][n][m] ----
  unsigned short* pb = part + (size_t)kc * PART_KC;
#pragma unroll
  for (int mt = 0; mt < 4; ++mt) {
    const int m0 = m0b + mg * 64 + mt * 16 + (lane >> 4) * 4;
#pragma unroll
    for (int nt = 0; nt < 2; ++nt) {
      const int n = n0b + ng * 32 + nt * 16 + l15;
      bf16x4 v;
      v[0] = (short)f2bf(acc[mt][nt][0]);
      v[1] = (short)f2bf(acc[mt][nt][1]);
      v[2] = (short)f2bf(acc[mt][nt][2]);
      v[3] = (short)f2bf(acc[mt][nt][3]);
      *(bf16x4*)&pb[(size_t)n * MSTRIDE + m0] = v;
    }
  }
}

// ---------------- Stage 2: kc-reduce + bias + ReLU + m-reductions ----------
__global__ __launch_bounds__(256) void k_colbuf(
    const unsigned short* __restrict__ part, const float* __restrict__ b3,
    const float* __restrict__ w4, const float* __restrict__ b4,
    float* __restrict__ colbuf)
{
  __shared__ float red[2][4];
  const int n = blockIdx.x;
  const int t = threadIdx.x;
  const unsigned short* p = part + (size_t)n * MSTRIDE + t;
  float s = 0.f;
#pragma unroll
  for (int kcc = 0; kcc < KSPLIT; ++kcc)
    s += bf2f(p[(size_t)kcc * PART_KC]);
  float e = 0.f, c4 = 0.f;
  if (t < C2) {
    e  = fmaxf(s + b3[t], 0.f);
    c4 = w4[t] * e;
  }
#pragma unroll
  for (int off = 32; off; off >>= 1) {
    e  += __shfl_xor(e, off);
    c4 += __shfl_xor(c4, off);
  }
  const int wv = t >> 6;
  if ((t & 63) == 0) { red[0][wv] = e; red[1][wv] = c4; }
  __syncthreads();
  if (t == 0) {
    const float cs  = red[0][0] + red[0][1] + red[0][2] + red[0][3];
    const float tc4 = red[1][0] + red[1][1] + red[1][2] + red[1][3] + b4[0];
    const float mask = 1.f / (1.f + expf(-tc4));
    colbuf[n] = cs * (1.f + mask) * (1.f / (float)L_DIM);
  }
}

// ---------------- Stage 3: broadcast to all nodes (R8 form, proven) --------
__global__ __launch_bounds__(256) void k_broadcast(
    const float* __restrict__ colbuf, float4* __restrict__ out)
{
  const size_t idx = (size_t)blockIdx.x * 256 + threadIdx.x;  // float4 index
  const int nq = (int)(idx & 255);
  const float4 v = *(const float4*)(colbuf + nq * 4);
  out[idx] = v;
}

extern "C" void kernel_launch(void* const* d_in, const int* in_sizes, int n_in,
                              void* d_out, int out_size, void* d_ws, size_t ws_size,
                              hipStream_t stream) {
  // inputs: x, edge_index, edge_attr, conv3_w, conv3_b, conv4_w, conv4_b
  const float* edge_attr = (const float*)d_in[2];   // [8192][1024]
  const float* w3        = (const float*)d_in[3];   // [240][8192]
  const float* b3        = (const float*)d_in[4];   // [240]
  const float* w4        = (const float*)d_in[5];   // [240]
  const float* b4        = (const float*)d_in[6];   // [1]

  float* out = (float*)d_out;

  // partials in d_ws (measured ws_size ~268MB >> 8.4MB); colbuf after them.
  unsigned short* part;
  float* colbuf;
  if (ws_size >= PART_BYTES + 4096) {
    part   = (unsigned short*)d_ws;
    colbuf = (float*)((char*)d_ws + PART_BYTES);
  } else {
    part   = (unsigned short*)d_out;   // overwritten by broadcast afterwards
    colbuf = (float*)d_ws;
  }

  // MEASUREMENT: k_gemm launched 3x (idempotent, deterministic).
  // g' = (total - ~9.5us of colbuf+bcast physics) / 3. Drop to 1x next round.
  k_gemm      <<<dim3(256),   512, 0, stream>>>(w3, edge_attr, part);
  k_gemm      <<<dim3(256),   512, 0, stream>>>(w3, edge_attr, part);
  k_gemm      <<<dim3(256),   512, 0, stream>>>(w3, edge_attr, part);
  k_colbuf    <<<dim3(1024),  256, 0, stream>>>(part, b3, w4, b4, colbuf);
  k_broadcast <<<dim3(10000), 256, 0, stream>>>(colbuf, (float4*)out);
}

// Round 15
// 32.083 us; speedup vs baseline: 1.8963x; 1.8963x over previous
//
#include <hip/hip_runtime.h>
#include <hip/hip_bf16.h>

#define K_DIM 8192
#define L_DIM 1024
#define C2 240
#define MSTRIDE 256                 // padded m stride in partials
#define BM 128
#define BN 128
#define BK 64
#define KSPLIT 16
#define KCHUNK 512                  // K_DIM / KSPLIT
#define NSTEP 8                     // KCHUNK / BK
#define DEPTH 5                     // prefetch depth: 12 loads/step x5 = 60 <= 63 vmcnt cap
#define PART_KC (L_DIM * MSTRIDE)   // 262144 bf16 elems per k-chunk
#define PART_BYTES ((size_t)KSPLIT * PART_KC * 2)  // 8,388,608
#define TOT_F4 (10000 * 256)

typedef __attribute__((ext_vector_type(4))) float f32x4;
typedef __attribute__((ext_vector_type(2))) float f32x2;
typedef __attribute__((ext_vector_type(8))) short bf16x8;
typedef __attribute__((ext_vector_type(4))) short bf16x4;

__device__ __forceinline__ unsigned short f2bf(float f) {
  return __builtin_bit_cast(unsigned short, __float2bfloat16(f));
}
__device__ __forceinline__ float bf2f(unsigned short h) {
  unsigned u = ((unsigned)h) << 16;
  return __builtin_bit_cast(float, u);
}

// lgkm-only barrier: ds ops visible across the barrier, but in-flight GLOBAL
// loads stay pending (HIP __syncthreads emits s_waitcnt vmcnt(0) and would
// drain the DEPTH*12 outstanding prefetch loads every step).
// R13/R14 A/B: depth-2+this = null vs R8, depth-4+this = GEMM 22 -> ~15-17us
// (congested-latency/DEPTH model confirmed).
__device__ __forceinline__ void barrier_lgkm_only() {
  __builtin_amdgcn_sched_barrier(0);
  asm volatile("s_waitcnt lgkmcnt(0)" ::: "memory");
  __builtin_amdgcn_s_barrier();
  __builtin_amdgcn_sched_barrier(0);
}

// ---------------- Stage 1: bf16 MFMA K-split GEMM, depth-5 prefetch --------
// part[kc][n][m(pad 256)] = (W[240][8192] @ A[8192][1024]) k-chunk partials.
// 256 blocks x 512 thr (8 waves: 2m x 4n of 64x32). KSPLIT=16, NSTEP=8.
// Step time ~= congested-load-latency / DEPTH: loads for step s+5 issue at
// step s, consumed by staging(s+5) under compiler-counted vmcnt. Slot s%5
// is compile-time (loop fully unrolled). VGPR: 5x32 prefetch + addr ~200.
__global__ __launch_bounds__(512, 2) void k_gemm(
    const float* __restrict__ Wm, const float* __restrict__ Am,
    unsigned short* __restrict__ part)
{
  __shared__ __align__(16) unsigned short sW[2 * BM * BK];  // 32 KB dbuf
  __shared__ __align__(16) unsigned short sA[2 * BN * BK];  // 32 KB dbuf

  const int t    = threadIdx.x;
  const int lane = t & 63;
  const int bid  = blockIdx.x;

  // XCD-chunked remap (bijective, 256 % 8 == 0): XCD owns 2 kc x all tiles.
  const int wk    = (bid & 7) * 32 + (bid >> 3);
  const int nt8   = wk & 7;
  const int mtile = (wk >> 3) & 1;
  const int kc    = wk >> 4;            // 0..15

  const int wid = t >> 6;
  const int mg  = wid >> 2;       // 2 groups of 64 m
  const int ng  = wid & 3;        // 4 groups of 32 n
  const int l15 = lane & 15;
  const int lk8 = (lane >> 4) * 8;

  const int n0b = nt8 * BN;
  const int m0b = mtile * BM;
  const int k0  = kc * KCHUNK;

  // W staging: thread -> (row t>>2, 16 k at (t&3)*16); 4 f32x4 loads.
  const int swm = t >> 2;
  const int swk = (t & 3) * 16;
  // A staging: thread -> (2 cols at 2*(t&63), 8 k at wid*8); 8 f32x2 loads.
  const int san = (t & 63) * 2;
  const int sak = (t >> 6) * 8;

  const float* wp = Wm + (size_t)(m0b + swm) * K_DIM + k0 + swk;
  const float* ap = Am + (size_t)(k0 + sak) * L_DIM + n0b + san;
  const bool wok = (m0b + swm) < C2;

  f32x4 wregs[DEPTH][4];
  f32x2 aregs[DEPTH][8];
  f32x4 acc[4][2];
#pragma unroll
  for (int i = 0; i < 4; ++i)
#pragma unroll
    for (int j = 0; j < 2; ++j) acc[i][j] = (f32x4){0.f, 0.f, 0.f, 0.f};

  // prologue: issue loads for steps 0..4 (depth-5)
#pragma unroll
  for (int p = 0; p < DEPTH; ++p) {
#pragma unroll
    for (int j = 0; j < 4; ++j)
      wregs[p][j] = wok ? *(const f32x4*)(wp + p * BK + 4 * j)
                        : (f32x4){0.f, 0.f, 0.f, 0.f};
#pragma unroll
    for (int r = 0; r < 8; ++r)
      aregs[p][r] = *(const f32x2*)(ap + (size_t)(p * BK + r) * L_DIM);
  }

#pragma unroll
  for (int s = 0; s < NSTEP; ++s) {
    unsigned short* swb = sW + (s & 1) * (BM * BK);
    unsigned short* sab = sA + (s & 1) * (BN * BK);
    const int slot = s % DEPTH;        // compile-time under full unroll

    // ---- convert + swizzled LDS write from reg slot (counted vmcnt) ----
#pragma unroll
    for (int j = 0; j < 2; ++j) {       // two bf16x8 per thread (16 k)
      f32x4 a = wregs[slot][2 * j], b = wregs[slot][2 * j + 1];
      bf16x8 v;
      v[0] = (short)f2bf(a[0]); v[1] = (short)f2bf(a[1]);
      v[2] = (short)f2bf(a[2]); v[3] = (short)f2bf(a[3]);
      v[4] = (short)f2bf(b[0]); v[5] = (short)f2bf(b[1]);
      v[6] = (short)f2bf(b[2]); v[7] = (short)f2bf(b[3]);
      *(bf16x8*)&swb[swm * BK + ((swk + 8 * j) ^ ((swm & 7) << 3))] = v;
    }
#pragma unroll
    for (int j = 0; j < 2; ++j) {       // two cols, 8 k each
      const int n = san + j;
      bf16x8 v;
#pragma unroll
      for (int r = 0; r < 8; ++r)
        v[r] = (short)f2bf(j ? aregs[slot][r][1] : aregs[slot][r][0]);
      *(bf16x8*)&sab[n * BK + (sak ^ ((n & 7) << 3))] = v;
    }

    barrier_lgkm_only();   // keeps the prefetch loads in flight

    // ---- issue loads for step s+5 into the just-freed slot ----
    if (s + DEPTH < NSTEP) {
      const float* wp2 = wp + (s + DEPTH) * BK;
      const float* ap2 = ap + (size_t)(s + DEPTH) * BK * L_DIM;
#pragma unroll
      for (int j = 0; j < 4; ++j)
        wregs[slot][j] = wok ? *(const f32x4*)(wp2 + 4 * j)
                             : (f32x4){0.f, 0.f, 0.f, 0.f};
#pragma unroll
      for (int r = 0; r < 8; ++r)
        aregs[slot][r] = *(const f32x2*)(ap2 + (size_t)r * L_DIM);
    }

    // ---- compute from LDS buffer s&1 ----
#pragma unroll
    for (int kk = 0; kk < BK; kk += 32) {
      bf16x8 wf[4], af[2];
#pragma unroll
      for (int mt = 0; mt < 4; ++mt) {
        int m = mg * 64 + mt * 16 + l15;
        wf[mt] = *(const bf16x8*)&swb[m * BK + ((kk + lk8) ^ ((m & 7) << 3))];
      }
#pragma unroll
      for (int nt = 0; nt < 2; ++nt) {
        int n = ng * 32 + nt * 16 + l15;
        af[nt] = *(const bf16x8*)&sab[n * BK + ((kk + lk8) ^ ((n & 7) << 3))];
      }
#pragma unroll
      for (int mt = 0; mt < 4; ++mt)
#pragma unroll
        for (int nt = 0; nt < 2; ++nt)
          acc[mt][nt] = __builtin_amdgcn_mfma_f32_16x16x32_bf16(
              wf[mt], af[nt], acc[mt][nt], 0, 0, 0);
    }
    // single barrier/step: next iteration writes the other LDS buffer
  }

  // ---- store transposed bf16 partials: part[kc][n][m] ----
  unsigned short* pb = part + (size_t)kc * PART_KC;
#pragma unroll
  for (int mt = 0; mt < 4; ++mt) {
    const int m0 = m0b + mg * 64 + mt * 16 + (lane >> 4) * 4;
#pragma unroll
    for (int nt = 0; nt < 2; ++nt) {
      const int n = n0b + ng * 32 + nt * 16 + l15;
      bf16x4 v;
      v[0] = (short)f2bf(acc[mt][nt][0]);
      v[1] = (short)f2bf(acc[mt][nt][1]);
      v[2] = (short)f2bf(acc[mt][nt][2]);
      v[3] = (short)f2bf(acc[mt][nt][3]);
      *(bf16x4*)&pb[(size_t)n * MSTRIDE + m0] = v;
    }
  }
}

// ---------------- Stage 2: kc-reduce + bias + ReLU + m-reductions ----------
__global__ __launch_bounds__(256) void k_colbuf(
    const unsigned short* __restrict__ part, const float* __restrict__ b3,
    const float* __restrict__ w4, const float* __restrict__ b4,
    float* __restrict__ colbuf)
{
  __shared__ float red[2][4];
  const int n = blockIdx.x;
  const int t = threadIdx.x;
  const unsigned short* p = part + (size_t)n * MSTRIDE + t;
  float s = 0.f;
#pragma unroll
  for (int kcc = 0; kcc < KSPLIT; ++kcc)
    s += bf2f(p[(size_t)kcc * PART_KC]);
  float e = 0.f, c4 = 0.f;
  if (t < C2) {
    e  = fmaxf(s + b3[t], 0.f);
    c4 = w4[t] * e;
  }
#pragma unroll
  for (int off = 32; off; off >>= 1) {
    e  += __shfl_xor(e, off);
    c4 += __shfl_xor(c4, off);
  }
  const int wv = t >> 6;
  if ((t & 63) == 0) { red[0][wv] = e; red[1][wv] = c4; }
  __syncthreads();
  if (t == 0) {
    const float cs  = red[0][0] + red[0][1] + red[0][2] + red[0][3];
    const float tc4 = red[1][0] + red[1][1] + red[1][2] + red[1][3] + b4[0];
    const float mask = 1.f / (1.f + expf(-tc4));
    colbuf[n] = cs * (1.f + mask) * (1.f / (float)L_DIM);
  }
}

// ---------------- Stage 3: broadcast to all nodes (R8 form, proven) --------
__global__ __launch_bounds__(256) void k_broadcast(
    const float* __restrict__ colbuf, float4* __restrict__ out)
{
  const size_t idx = (size_t)blockIdx.x * 256 + threadIdx.x;  // float4 index
  const int nq = (int)(idx & 255);
  const float4 v = *(const float4*)(colbuf + nq * 4);
  out[idx] = v;
}

extern "C" void kernel_launch(void* const* d_in, const int* in_sizes, int n_in,
                              void* d_out, int out_size, void* d_ws, size_t ws_size,
                              hipStream_t stream) {
  // inputs: x, edge_index, edge_attr, conv3_w, conv3_b, conv4_w, conv4_b
  const float* edge_attr = (const float*)d_in[2];   // [8192][1024]
  const float* w3        = (const float*)d_in[3];   // [240][8192]
  const float* b3        = (const float*)d_in[4];   // [240]
  const float* w4        = (const float*)d_in[5];   // [240]
  const float* b4        = (const float*)d_in[6];   // [1]

  float* out = (float*)d_out;

  // partials in d_ws (measured ws_size ~268MB >> 8.4MB); colbuf after them.
  unsigned short* part;
  float* colbuf;
  if (ws_size >= PART_BYTES + 4096) {
    part   = (unsigned short*)d_ws;
    colbuf = (float*)((char*)d_ws + PART_BYTES);
  } else {
    part   = (unsigned short*)d_out;   // overwritten by broadcast afterwards
    colbuf = (float*)d_ws;
  }

  k_gemm      <<<dim3(256),   512, 0, stream>>>(w3, edge_attr, part);
  k_colbuf    <<<dim3(1024),  256, 0, stream>>>(part, b3, w4, b4, colbuf);
  k_broadcast <<<dim3(10000), 256, 0, stream>>>(colbuf, (float4*)out);
}